// Round 8
// baseline (494.230 us; speedup 1.0000x reference)
//
#include <hip/hip_runtime.h>

#define N_NODES 50000
#define N_EDGES 800000
#define E_TOT   850000   /* N_EDGES + N_NODES self-loops */
#define C_IN    512
#define C_HID   128
#define NEG     0.2f

typedef _Float16 f16x8 __attribute__((ext_vector_type(8)));
typedef __attribute__((ext_vector_type(4))) float f32x4;

__device__ __forceinline__ float leaky(float x) { return x > 0.f ? x : NEG * x; }

union U32H2 { unsigned u; _Float16 h[2]; float f; };
union BFrag { uint4 u; f16x8 h; };

__device__ __forceinline__ unsigned short f2h(float f) {
  U32H2 c; c.h[0] = (_Float16)f; return (unsigned short)(c.u & 0xffff);
}

// pack two fp32 -> fp16x2 (RTZ hardware op) as raw u32
__device__ __forceinline__ unsigned pk2h(float a, float b) {
  union { __fp16 v __attribute__((ext_vector_type(2))); unsigned u; } c;
  c.v = __builtin_amdgcn_cvt_pkrtz(a, b);
  return c.u;
}

// ---------------------------------------------------------------------------
// prep_v: v1s[k] = sum_c W1[k,c]*att_src1[c], v1d likewise. Wave per k row.
// ---------------------------------------------------------------------------
__global__ __launch_bounds__(256) void prep_v_kernel(const float* __restrict__ W1,
    const float* __restrict__ as1, const float* __restrict__ ad1,
    float* __restrict__ v1s, float* __restrict__ v1d) {
  const int wv = threadIdx.x >> 6, lane = threadIdx.x & 63;
  const int k = blockIdx.x * 4 + wv;
  if (k >= C_IN) return;
  float2 w = *(const float2*)(W1 + (size_t)k * C_HID + 2 * lane);
  float2 a = *(const float2*)(as1 + 2 * lane);
  float2 d = *(const float2*)(ad1 + 2 * lane);
  float s = w.x * a.x + w.y * a.y;
  float t = w.x * d.x + w.y * d.y;
#pragma unroll
  for (int m = 32; m >= 1; m >>= 1) {
    s += __shfl_xor(s, m, 64);
    t += __shfl_xor(t, m, 64);
  }
  if (lane == 0) { v1s[k] = s; v1d[k] = t; }
}

// ---------------------------------------------------------------------------
// prep_w: W1 [512][128] fp32 -> MFMA-fragment-order fp16 hi/lo swizzle.
// ---------------------------------------------------------------------------
__global__ __launch_bounds__(256) void prep_w_kernel(const float* __restrict__ W1,
    unsigned short* __restrict__ Wswz) {
  int t = blockIdx.x * 256 + threadIdx.x;          // 8192 threads
  int c = t >> 6, kc = t & 63;                     // c in [0,128), k = kc*8
  if (c >= C_HID) return;
  int kblk = kc >> 2, q = kc & 3;
  int ct = c >> 4, l15 = c & 15;
  int lane = q * 16 + l15;
  unsigned short hb[8], lb[8];
#pragma unroll
  for (int i = 0; i < 8; i++) {
    float w = W1[(size_t)(kc * 8 + i) * C_HID + c];
    _Float16 hi = (_Float16)w;                     // RNE
    _Float16 lo = (_Float16)(w - (float)hi);
    U32H2 ch; ch.h[0] = hi;
    U32H2 cl; cl.h[0] = lo;
    hb[i] = (unsigned short)(ch.u & 0xffff);
    lb[i] = (unsigned short)(cl.u & 0xffff);
  }
  size_t chunk0 = ((size_t)(kblk * 8 + ct) * 2) * 512;   // ushort units
  *(uint4*)&Wswz[chunk0 + (size_t)lane * 8]       = *(uint4*)hb;
  *(uint4*)&Wswz[chunk0 + 512 + (size_t)lane * 8] = *(uint4*)lb;
}

// ---------------------------------------------------------------------------
// lin1: h1 = x @ W1 via fp16 MFMA, fused fp32 a_src/a_dst.
// Block 64x128, 4 waves; wave owns 64 rows x 32 cols; B direct global->reg.
// h1 stored fp16 in CHANNEL-GROUP-SHARDED layout:
//   h1g[(col>>5)*N*32 + row*32 + (col&31)]  (4 tables of 3.2 MB)
// ---------------------------------------------------------------------------
__global__ __launch_bounds__(256) void lin1_kernel(const float* __restrict__ x,
    const unsigned short* __restrict__ Wswz,
    const float* __restrict__ v1s, const float* __restrict__ v1d,
    unsigned short* __restrict__ h1g, float* __restrict__ a_src, float* __restrict__ a_dst) {
  __shared__ __attribute__((aligned(16))) unsigned short As[64][40];

  const int tid  = threadIdx.x;
  const int lane = tid & 63, wv = tid >> 6;
  const int m0   = blockIdx.x * 64;

  const int arow = tid >> 2, kseg = (tid & 3) * 8;
  int grow = m0 + arow;
  if (grow >= N_NODES) grow = N_NODES - 1;          // clamp; stores guarded
  const float* xrow = x + (size_t)grow * C_IN + kseg;

  f32x4 acc[4][2];
#pragma unroll
  for (int rt = 0; rt < 4; rt++) { acc[rt][0] = (f32x4)0.f; acc[rt][1] = (f32x4)0.f; }
  float ps = 0.f, pd = 0.f;

  const int q = lane >> 4, l15 = lane & 15;

  float4 xa = *(const float4*)(xrow);
  float4 xb = *(const float4*)(xrow + 4);

  for (int kblk = 0; kblk < 16; kblk++) {
    const int k0 = kblk * 32;
    float4 vsa = *(const float4*)(v1s + k0 + kseg);
    float4 vsb = *(const float4*)(v1s + k0 + kseg + 4);
    float4 vda = *(const float4*)(v1d + k0 + kseg);
    float4 vdb = *(const float4*)(v1d + k0 + kseg + 4);
    ps += xa.x * vsa.x + xa.y * vsa.y + xa.z * vsa.z + xa.w * vsa.w
        + xb.x * vsb.x + xb.y * vsb.y + xb.z * vsb.z + xb.w * vsb.w;
    pd += xa.x * vda.x + xa.y * vda.y + xa.z * vda.z + xa.w * vda.w
        + xb.x * vdb.x + xb.y * vdb.y + xb.z * vdb.z + xb.w * vdb.w;
    uint4 pk = make_uint4(pk2h(xa.x, xa.y), pk2h(xa.z, xa.w),
                          pk2h(xb.x, xb.y), pk2h(xb.z, xb.w));

    __syncthreads();
    *(uint4*)&As[arow][kseg] = pk;
    if (kblk < 15) {
      xa = *(const float4*)(xrow + k0 + 32);
      xb = *(const float4*)(xrow + k0 + 36);
    }
    __syncthreads();

    const unsigned short* bp = Wswz + ((size_t)(kblk * 8 + wv * 2) * 2) * 512 + (size_t)lane * 8;
    BFrag b00, b01, b10, b11;
    b00.u = *(const uint4*)(bp);
    b01.u = *(const uint4*)(bp + 512);
    b10.u = *(const uint4*)(bp + 1024);
    b11.u = *(const uint4*)(bp + 1536);

#pragma unroll
    for (int rt = 0; rt < 4; rt++) {
      f16x8 af = *(const f16x8*)&As[rt * 16 + l15][q * 8];
      acc[rt][0] = __builtin_amdgcn_mfma_f32_16x16x32_f16(af, b00.h, acc[rt][0], 0, 0, 0);
      acc[rt][0] = __builtin_amdgcn_mfma_f32_16x16x32_f16(af, b01.h, acc[rt][0], 0, 0, 0);
      acc[rt][1] = __builtin_amdgcn_mfma_f32_16x16x32_f16(af, b10.h, acc[rt][1], 0, 0, 0);
      acc[rt][1] = __builtin_amdgcn_mfma_f32_16x16x32_f16(af, b11.h, acc[rt][1], 0, 0, 0);
    }
  }

  ps += __shfl_xor(ps, 1, 64); ps += __shfl_xor(ps, 2, 64);
  pd += __shfl_xor(pd, 1, 64); pd += __shfl_xor(pd, 2, 64);
  if ((tid & 3) == 0) {
    int row = m0 + arow;
    if (row < N_NODES) { a_src[row] = ps; a_dst[row] = pd; }
  }

  // C store (fp16) into group-sharded layout: col = wv*32 + ct*16 + l15
#pragma unroll
  for (int rt = 0; rt < 4; rt++) {
    int rbase = m0 + rt * 16 + q * 4;
#pragma unroll
    for (int ct = 0; ct < 2; ct++) {
#pragma unroll
      for (int ri = 0; ri < 4; ri++) {
        int row = rbase + ri;
        if (row < N_NODES)
          h1g[(size_t)wv * N_NODES * 32 + (size_t)row * 32 + ct * 16 + l15]
              = f2h(acc[rt][ct][ri]);
      }
    }
  }
}

// ---------------------------------------------------------------------------
// CSR build
// ---------------------------------------------------------------------------
__global__ void deg_kernel(const int* __restrict__ ei, int* __restrict__ deg) {
  int e = blockIdx.x * blockDim.x + threadIdx.x;
  if (e >= N_EDGES) return;
  atomicAdd(&deg[ei[N_EDGES + e]], 1);
}

__global__ __launch_bounds__(1024) void scan_kernel(const int* __restrict__ deg,
                                                    int* __restrict__ rowptr,
                                                    int* __restrict__ cursor) {
  __shared__ int wsum[16];
  const int tid = threadIdx.x, lane = tid & 63, wv = tid >> 6;
  int carry = 0;
  for (int base = 0; base < N_NODES; base += 8192) {   // 7 chunks
    int i0 = base + tid * 8;
    int v[8];
    if (i0 + 8 <= N_NODES) {
      int4 va = *(const int4*)(deg + i0);
      int4 vb = *(const int4*)(deg + i0 + 4);
      v[0]=va.x+1; v[1]=va.y+1; v[2]=va.z+1; v[3]=va.w+1;
      v[4]=vb.x+1; v[5]=vb.y+1; v[6]=vb.z+1; v[7]=vb.w+1;
    } else {
#pragma unroll
      for (int i = 0; i < 8; i++) v[i] = (i0 + i < N_NODES) ? deg[i0 + i] + 1 : 0;
    }
    int tsum = 0;
#pragma unroll
    for (int i = 0; i < 8; i++) tsum += v[i];
    int sc = tsum;
#pragma unroll
    for (int off = 1; off < 64; off <<= 1) {
      int t = __shfl_up(sc, off, 64);
      if (lane >= off) sc += t;
    }
    if (lane == 63) wsum[wv] = sc;
    __syncthreads();
    if (wv == 0 && lane < 16) {
      int s = wsum[lane];
#pragma unroll
      for (int off = 1; off < 16; off <<= 1) {
        int t = __shfl_up(s, off, 64);
        if (lane >= off) s += t;
      }
      wsum[lane] = s;
    }
    __syncthreads();
    int ex = carry + (wv ? wsum[wv - 1] : 0) + sc - tsum;
#pragma unroll
    for (int i = 0; i < 8; i++) {
      if (i0 + i < N_NODES) { rowptr[i0 + i] = ex; cursor[i0 + i] = ex; }
      ex += v[i];
    }
    carry += wsum[15];
    __syncthreads();
  }
  if (tid == 0) rowptr[N_NODES] = carry;
}

__global__ void bucket_kernel(const int* __restrict__ ei, int* __restrict__ cursor,
                              const float* __restrict__ a_src, const float* __restrict__ a_dst,
                              int2* __restrict__ esw) {
  int e = blockIdx.x * blockDim.x + threadIdx.x;
  if (e >= E_TOT) return;
  int src, dst;
  if (e < N_EDGES) { src = ei[e]; dst = ei[N_EDGES + e]; }
  else             { src = dst = e - N_EDGES; }
  float w = __expf(leaky(a_src[src] + a_dst[dst]));
  int slot = atomicAdd(&cursor[dst], 1);
  U32H2 c; c.f = w;
  esw[slot] = make_int2(src, (int)c.u);
}

// ---------------------------------------------------------------------------
// agg1: block = (node-quad, group g = blockIdx&3); group table 3.2 MB is
// XCD-L2-resident (blockIdx%8 round-robin => XCD x serves only group x&3).
// Wave per node; lane = (e in [0,16), f in [0,4)): lane gathers the 16-B
// quarter f of edge slot 16i+e's 64-B group row -> one gather inst covers
// 16 edges (same inst economics as the unsharded R6 kernel). Fold over e via
// shfl_xor(4/8/16/32). Epilogue: group-local ReLU + partial W2 -> h2p[g][n]
// non-atomic; combine_kernel sums the 4 partials.
// ---------------------------------------------------------------------------
__global__ __launch_bounds__(256) void agg1_kernel(const unsigned short* __restrict__ h1g,
    const int2* __restrict__ esw, const int* __restrict__ rowptr,
    const float* __restrict__ bias1, const float* __restrict__ W2,
    float* __restrict__ h2p) {
  const int wv = threadIdx.x >> 6, lane = threadIdx.x & 63;
  const int e = lane >> 2, f = lane & 3;
  const int g = blockIdx.x & 3;
  const int n = (blockIdx.x >> 2) * 4 + wv;        // grid = (N/4)*4 exact

  const int start = rowptr[n], end = rowptr[n + 1];
  const unsigned short* tbl = h1g + (size_t)g * N_NODES * 32 + f * 8;

  float acc[8] = {0, 0, 0, 0, 0, 0, 0, 0};
  float wsum = 0.f;
  for (int base = start; base < end; base += 64) {
    int idx = base + lane;
    int sreg = 0; float wreg = 0.f;
    if (idx < end) {
      int2 sv = esw[idx];
      sreg = sv.x;
      U32H2 c; c.u = (unsigned)sv.y;
      wreg = c.f;
    }
    wsum += wreg;
    const int cnt = min(64, end - base);
#pragma unroll
    for (int i = 0; i < 4; i++) {
      if (i * 16 >= cnt) break;                    // wave-uniform guard
      int slot = i * 16 + e;
      int   s = __shfl(sreg, slot, 64);            // invalid slots: s=0,w=0
      float w = __shfl(wreg, slot, 64);
      uint4 gv = *(const uint4*)(tbl + (size_t)s * 32);
      U32H2 c0, c1, c2, c3;
      c0.u = gv.x; c1.u = gv.y; c2.u = gv.z; c3.u = gv.w;
      acc[0] = fmaf(w, (float)c0.h[0], acc[0]); acc[1] = fmaf(w, (float)c0.h[1], acc[1]);
      acc[2] = fmaf(w, (float)c1.h[0], acc[2]); acc[3] = fmaf(w, (float)c1.h[1], acc[3]);
      acc[4] = fmaf(w, (float)c2.h[0], acc[4]); acc[5] = fmaf(w, (float)c2.h[1], acc[5]);
      acc[6] = fmaf(w, (float)c3.h[0], acc[6]); acc[7] = fmaf(w, (float)c3.h[1], acc[7]);
    }
  }

  // fold over e (lane bits 2..5): every lane gets full sums for its 8 channels
#pragma unroll
  for (int i = 0; i < 8; i++) {
    acc[i] += __shfl_xor(acc[i], 4, 64);
    acc[i] += __shfl_xor(acc[i], 8, 64);
    acc[i] += __shfl_xor(acc[i], 16, 64);
    acc[i] += __shfl_xor(acc[i], 32, 64);
  }
#pragma unroll
  for (int m = 32; m >= 1; m >>= 1) wsum += __shfl_xor(wsum, m, 64);
  const float inv = 1.f / wsum;                    // > 0 via self-loop

  // epilogue: channels c = g*32 + f*8 + j
  const int c0i = g * 32 + f * 8;
  float4 ba = *(const float4*)(bias1 + c0i);
  float4 bb = *(const float4*)(bias1 + c0i + 4);
  float u[8] = {fmaxf(acc[0] * inv + ba.x, 0.f), fmaxf(acc[1] * inv + ba.y, 0.f),
                fmaxf(acc[2] * inv + ba.z, 0.f), fmaxf(acc[3] * inv + ba.w, 0.f),
                fmaxf(acc[4] * inv + bb.x, 0.f), fmaxf(acc[5] * inv + bb.y, 0.f),
                fmaxf(acc[6] * inv + bb.z, 0.f), fmaxf(acc[7] * inv + bb.w, 0.f)};
  float p[6] = {0, 0, 0, 0, 0, 0};
#pragma unroll
  for (int j = 0; j < 8; j++) {
    const float* w2r = W2 + (size_t)(c0i + j) * 6;
#pragma unroll
    for (int o = 0; o < 6; o++) p[o] = fmaf(u[j], w2r[o], p[o]);
  }
  // fold over f (lane bits 0..1)
#pragma unroll
  for (int o = 0; o < 6; o++) {
    p[o] += __shfl_xor(p[o], 1, 64);
    p[o] += __shfl_xor(p[o], 2, 64);
  }
  if (lane == 0) {
    float* dst = h2p + ((size_t)g * N_NODES + n) * 8;
    *(float4*)dst = make_float4(p[0], p[1], p[2], p[3]);
    *(float2*)(dst + 4) = make_float2(p[4], p[5]);
  }
}

// ---------------------------------------------------------------------------
// combine: h2[n] = sum_g h2p[g][n]; as2/ad2 from combined h2. Thread per node.
// ---------------------------------------------------------------------------
__global__ __launch_bounds__(256) void combine_kernel(const float* __restrict__ h2p,
    const float* __restrict__ as2w, const float* __restrict__ ad2w,
    float* __restrict__ h2, float* __restrict__ as2, float* __restrict__ ad2) {
  int n = blockIdx.x * 256 + threadIdx.x;
  if (n >= N_NODES) return;
  float p[6] = {0, 0, 0, 0, 0, 0};
#pragma unroll
  for (int g = 0; g < 4; g++) {
    const float* src = h2p + ((size_t)g * N_NODES + n) * 8;
    float4 a = *(const float4*)src;
    float2 b = *(const float2*)(src + 4);
    p[0] += a.x; p[1] += a.y; p[2] += a.z; p[3] += a.w; p[4] += b.x; p[5] += b.y;
  }
  *(float4*)(h2 + (size_t)n * 8) = make_float4(p[0], p[1], p[2], p[3]);
  *(float2*)(h2 + (size_t)n * 8 + 4) = make_float2(p[4], p[5]);
  float4 as, ad;
  as.x = p[0] * as2w[0] + p[1] * as2w[1];
  as.y = p[2] * as2w[2] + p[3] * as2w[3];
  as.z = p[4] * as2w[4] + p[5] * as2w[5];
  as.w = 0.f;
  ad.x = p[0] * ad2w[0] + p[1] * ad2w[1];
  ad.y = p[2] * ad2w[2] + p[3] * ad2w[3];
  ad.z = p[4] * ad2w[4] + p[5] * ad2w[5];
  ad.w = 0.f;
  *(float4*)(as2 + (size_t)n * 4) = as;
  *(float4*)(ad2 + (size_t)n * 4) = ad;
}

// ---------------------------------------------------------------------------
// agg2: 16 lanes per node (4 nodes/wave), lanes strided over edges,
// single pass, 4-step reductions. out = mean over heads + bias2.
// ---------------------------------------------------------------------------
__global__ __launch_bounds__(256) void agg2_kernel(const float* __restrict__ h2,
    const float* __restrict__ as2, const float* __restrict__ ad2,
    const int* __restrict__ rowptr, const int2* __restrict__ esw,
    const float* __restrict__ bias2, float* __restrict__ out) {
  const int wv = threadIdx.x >> 6, lane = threadIdx.x & 63;
  const int q = lane >> 4, r = lane & 15;
  const int n = blockIdx.x * 16 + wv * 4 + q;
  if (n >= N_NODES) return;
  const int start = rowptr[n], end = rowptr[n + 1];
  const float4 adv = *(const float4*)(ad2 + (size_t)n * 4);

  float d0 = 0.f, d1 = 0.f, d2 = 0.f;
  float a0 = 0.f, a1 = 0.f, a2 = 0.f, a3 = 0.f, a4 = 0.f, a5 = 0.f;
  for (int j = start + r; j < end; j += 16) {
    int s = esw[j].x;
    float4 asv = *(const float4*)(as2 + (size_t)s * 4);
    float4 hlo = *(const float4*)(h2 + (size_t)s * 8);
    float2 hhi = *(const float2*)(h2 + (size_t)s * 8 + 4);
    float e0 = __expf(leaky(asv.x + adv.x));
    float e1 = __expf(leaky(asv.y + adv.y));
    float e2 = __expf(leaky(asv.z + adv.z));
    d0 += e0; d1 += e1; d2 += e2;
    a0 += e0 * hlo.x; a1 += e0 * hlo.y;
    a2 += e1 * hlo.z; a3 += e1 * hlo.w;
    a4 += e2 * hhi.x; a5 += e2 * hhi.y;
  }
#pragma unroll
  for (int m = 8; m >= 1; m >>= 1) {
    d0 += __shfl_xor(d0, m, 64); d1 += __shfl_xor(d1, m, 64); d2 += __shfl_xor(d2, m, 64);
    a0 += __shfl_xor(a0, m, 64); a1 += __shfl_xor(a1, m, 64); a2 += __shfl_xor(a2, m, 64);
    a3 += __shfl_xor(a3, m, 64); a4 += __shfl_xor(a4, m, 64); a5 += __shfl_xor(a5, m, 64);
  }
  if (r == 0) {
    float o0 = (a0 / d0 + a2 / d1 + a4 / d2) * (1.f / 3.f) + bias2[0];
    float o1 = (a1 / d0 + a3 / d1 + a5 / d2) * (1.f / 3.f) + bias2[1];
    *(float2*)(out + (size_t)n * 2) = make_float2(o0, o1);
  }
}

// ---------------------------------------------------------------------------
extern "C" void kernel_launch(void* const* d_in, const int* in_sizes, int n_in,
                              void* d_out, int out_size, void* d_ws, size_t ws_size,
                              hipStream_t stream) {
  const float* x        = (const float*)d_in[0];
  const int*   ei       = (const int*)d_in[1];
  const float* W1       = (const float*)d_in[2];
  const float* att_src1 = (const float*)d_in[3];
  const float* att_dst1 = (const float*)d_in[4];
  const float* bias1    = (const float*)d_in[5];
  const float* W2       = (const float*)d_in[6];
  const float* att_src2 = (const float*)d_in[7];
  const float* att_dst2 = (const float*)d_in[8];
  const float* bias2    = (const float*)d_in[9];
  float* out = (float*)d_out;

  char* w = (char*)d_ws;
  auto alloc = [&](size_t bytes) {
    char* p = w;
    w += (bytes + 255) & ~(size_t)255;
    return p;
  };
  unsigned short* h1g    = (unsigned short*)alloc((size_t)N_NODES * C_HID * 2);  // 12.8 MB (4 x 3.2 MB)
  unsigned short* Wswz   = (unsigned short*)alloc((size_t)C_IN * C_HID * 2 * 2); // 256 KB
  float*          v1s    = (float*)alloc((size_t)C_IN * 4);
  float*          v1d    = (float*)alloc((size_t)C_IN * 4);
  float*          a_src1 = (float*)alloc((size_t)N_NODES * 4);
  float*          a_dst1 = (float*)alloc((size_t)N_NODES * 4);
  int*            deg    = (int*)alloc((size_t)N_NODES * 4);
  int*            rowptr = (int*)alloc((size_t)(N_NODES + 4) * 4);
  int*            cursor = (int*)alloc((size_t)N_NODES * 4);
  int2*           esw    = (int2*)alloc((size_t)E_TOT * 8);                      // 6.8 MB
  float*          h2p    = (float*)alloc((size_t)4 * N_NODES * 8 * 4);           // 6.4 MB partials
  float*          h2     = (float*)alloc((size_t)N_NODES * 8 * 4);
  float*          as2    = (float*)alloc((size_t)N_NODES * 4 * 4);
  float*          ad2    = (float*)alloc((size_t)N_NODES * 4 * 4);

  (void)hipMemsetAsync(deg, 0, (size_t)N_NODES * 4, stream);

  prep_v_kernel<<<C_IN / 4, 256, 0, stream>>>(W1, att_src1, att_dst1, v1s, v1d);
  prep_w_kernel<<<32, 256, 0, stream>>>(W1, Wswz);
  deg_kernel<<<(N_EDGES + 255) / 256, 256, 0, stream>>>(ei, deg);
  scan_kernel<<<1, 1024, 0, stream>>>(deg, rowptr, cursor);
  lin1_kernel<<<(N_NODES + 63) / 64, 256, 0, stream>>>(x, Wswz, v1s, v1d,
                                                       h1g, a_src1, a_dst1);
  bucket_kernel<<<(E_TOT + 255) / 256, 256, 0, stream>>>(ei, cursor, a_src1, a_dst1, esw);
  agg1_kernel<<<(N_NODES / 4) * 4, 256, 0, stream>>>(h1g, esw, rowptr, bias1, W2, h2p);
  combine_kernel<<<(N_NODES + 255) / 256, 256, 0, stream>>>(h2p, att_src2, att_dst2,
                                                            h2, as2, ad2);
  agg2_kernel<<<(N_NODES + 15) / 16, 256, 0, stream>>>(h2, as2, ad2, rowptr, esw, bias2, out);
}

// Round 9
// 328.635 us; speedup vs baseline: 1.5039x; 1.5039x over previous
//
#include <hip/hip_runtime.h>

#define N_NODES 50000
#define N_EDGES 800000
#define E_TOT   850000   /* N_EDGES + N_NODES self-loops */
#define C_IN    512
#define C_HID   128
#define NEG     0.2f

typedef _Float16 f16x8 __attribute__((ext_vector_type(8)));
typedef __attribute__((ext_vector_type(4))) float f32x4;

__device__ __forceinline__ float leaky(float x) { return x > 0.f ? x : NEG * x; }

union U32H2 { unsigned u; _Float16 h[2]; float f; };
union BFrag { uint4 u; f16x8 h; };

__device__ __forceinline__ unsigned short f2h(float f) {
  U32H2 c; c.h[0] = (_Float16)f; return (unsigned short)(c.u & 0xffff);
}

// pack two fp32 -> fp16x2 (RTZ hardware op) as raw u32
__device__ __forceinline__ unsigned pk2h(float a, float b) {
  union { __fp16 v __attribute__((ext_vector_type(2))); unsigned u; } c;
  c.v = __builtin_amdgcn_cvt_pkrtz(a, b);
  return c.u;
}

// ---------------------------------------------------------------------------
// setup: fuses prep_w (blocks 0..31), prep_v (32..159), deg+rank (160..3284).
//  prep_w: W1 -> MFMA-fragment-order fp16 hi/lo swizzle Wswz.
//  prep_v: v1s[k] = sum_c W1[k,c]*att_src1[c]; v1d likewise.
//  deg:    rank[e] = atomicAdd(deg[dst],1)  (edge's slot within its bucket).
// ---------------------------------------------------------------------------
__global__ __launch_bounds__(256) void setup_kernel(
    const float* __restrict__ W1, const float* __restrict__ as1,
    const float* __restrict__ ad1, const int* __restrict__ ei,
    unsigned short* __restrict__ Wswz, float* __restrict__ v1s, float* __restrict__ v1d,
    int* __restrict__ deg, int* __restrict__ rnk) {
  const int b = blockIdx.x;
  if (b < 32) {
    int t = b * 256 + threadIdx.x;                 // 8192 threads
    int c = t >> 6, kc = t & 63;
    if (c >= C_HID) return;
    int kblk = kc >> 2, q = kc & 3;
    int ct = c >> 4, l15 = c & 15;
    int lane = q * 16 + l15;
    unsigned short hb[8], lb[8];
#pragma unroll
    for (int i = 0; i < 8; i++) {
      float w = W1[(size_t)(kc * 8 + i) * C_HID + c];
      _Float16 hi = (_Float16)w;                   // RNE
      _Float16 lo = (_Float16)(w - (float)hi);
      U32H2 ch; ch.h[0] = hi;
      U32H2 cl; cl.h[0] = lo;
      hb[i] = (unsigned short)(ch.u & 0xffff);
      lb[i] = (unsigned short)(cl.u & 0xffff);
    }
    size_t chunk0 = ((size_t)(kblk * 8 + ct) * 2) * 512;
    *(uint4*)&Wswz[chunk0 + (size_t)lane * 8]       = *(uint4*)hb;
    *(uint4*)&Wswz[chunk0 + 512 + (size_t)lane * 8] = *(uint4*)lb;
  } else if (b < 160) {
    const int wv = threadIdx.x >> 6, lane = threadIdx.x & 63;
    const int k = (b - 32) * 4 + wv;
    if (k >= C_IN) return;
    float2 w = *(const float2*)(W1 + (size_t)k * C_HID + 2 * lane);
    float2 a = *(const float2*)(as1 + 2 * lane);
    float2 d = *(const float2*)(ad1 + 2 * lane);
    float s = w.x * a.x + w.y * a.y;
    float t = w.x * d.x + w.y * d.y;
#pragma unroll
    for (int m = 32; m >= 1; m >>= 1) {
      s += __shfl_xor(s, m, 64);
      t += __shfl_xor(t, m, 64);
    }
    if (lane == 0) { v1s[k] = s; v1d[k] = t; }
  } else {
    int e = (b - 160) * 256 + threadIdx.x;
    if (e < N_EDGES) rnk[e] = atomicAdd(&deg[ei[N_EDGES + e]], 1);
  }
}

// ---------------------------------------------------------------------------
// lin1: h1 = x @ W1 via fp16 MFMA (x_h*W_hi + x_h*W_lo), fused fp32 a_src/a_dst.
// Block 64x128, 4 waves; wave owns 64 rows x 32 cols; B direct global->reg
// (Wswz, L2-resident, coalesced). Double-buffered As -> ONE barrier per kblk;
// x prefetch issued after the barrier so it overlaps B-loads + MFMA.
// ---------------------------------------------------------------------------
__global__ __launch_bounds__(256) void lin1_kernel(const float* __restrict__ x,
    const unsigned short* __restrict__ Wswz,
    const float* __restrict__ v1s, const float* __restrict__ v1d,
    unsigned short* __restrict__ h1u, float* __restrict__ a_src, float* __restrict__ a_dst) {
  __shared__ __attribute__((aligned(16))) unsigned short As[2][64][40];  // 10 KB

  const int tid  = threadIdx.x;
  const int lane = tid & 63, wv = tid >> 6;
  const int m0   = blockIdx.x * 64;

  const int arow = tid >> 2, kseg = (tid & 3) * 8;
  int grow = m0 + arow;
  if (grow >= N_NODES) grow = N_NODES - 1;          // clamp; stores guarded
  const float* xrow = x + (size_t)grow * C_IN + kseg;

  f32x4 acc[4][2];
#pragma unroll
  for (int rt = 0; rt < 4; rt++) { acc[rt][0] = (f32x4)0.f; acc[rt][1] = (f32x4)0.f; }
  float ps = 0.f, pd = 0.f;

  const int q = lane >> 4, l15 = lane & 15;

  float4 xa = *(const float4*)(xrow);
  float4 xb = *(const float4*)(xrow + 4);

#pragma unroll
  for (int kblk = 0; kblk < 16; kblk++) {
    const int k0 = kblk * 32;
    const int buf = kblk & 1;
    float4 vsa = *(const float4*)(v1s + k0 + kseg);
    float4 vsb = *(const float4*)(v1s + k0 + kseg + 4);
    float4 vda = *(const float4*)(v1d + k0 + kseg);
    float4 vdb = *(const float4*)(v1d + k0 + kseg + 4);
    ps += xa.x * vsa.x + xa.y * vsa.y + xa.z * vsa.z + xa.w * vsa.w
        + xb.x * vsb.x + xb.y * vsb.y + xb.z * vsb.z + xb.w * vsb.w;
    pd += xa.x * vda.x + xa.y * vda.y + xa.z * vda.z + xa.w * vda.w
        + xb.x * vdb.x + xb.y * vdb.y + xb.z * vdb.z + xb.w * vdb.w;
    *(uint4*)&As[buf][arow][kseg] = make_uint4(pk2h(xa.x, xa.y), pk2h(xa.z, xa.w),
                                               pk2h(xb.x, xb.y), pk2h(xb.z, xb.w));
    __syncthreads();                                // As[buf] ready
    if (kblk < 15) {                                // prefetch next x chunk
      xa = *(const float4*)(xrow + k0 + 32);
      xb = *(const float4*)(xrow + k0 + 36);
    }

    const unsigned short* bp = Wswz + ((size_t)(kblk * 8 + wv * 2) * 2) * 512 + (size_t)lane * 8;
    BFrag b00, b01, b10, b11;
    b00.u = *(const uint4*)(bp);
    b01.u = *(const uint4*)(bp + 512);
    b10.u = *(const uint4*)(bp + 1024);
    b11.u = *(const uint4*)(bp + 1536);

#pragma unroll
    for (int rt = 0; rt < 4; rt++) {
      f16x8 af = *(const f16x8*)&As[buf][rt * 16 + l15][q * 8];
      acc[rt][0] = __builtin_amdgcn_mfma_f32_16x16x32_f16(af, b00.h, acc[rt][0], 0, 0, 0);
      acc[rt][0] = __builtin_amdgcn_mfma_f32_16x16x32_f16(af, b01.h, acc[rt][0], 0, 0, 0);
      acc[rt][1] = __builtin_amdgcn_mfma_f32_16x16x32_f16(af, b10.h, acc[rt][1], 0, 0, 0);
      acc[rt][1] = __builtin_amdgcn_mfma_f32_16x16x32_f16(af, b11.h, acc[rt][1], 0, 0, 0);
    }
  }

  // attention dots: reduce over the 4 staging threads sharing a row
  ps += __shfl_xor(ps, 1, 64); ps += __shfl_xor(ps, 2, 64);
  pd += __shfl_xor(pd, 1, 64); pd += __shfl_xor(pd, 2, 64);
  if ((tid & 3) == 0) {
    int row = m0 + arow;
    if (row < N_NODES) { a_src[row] = ps; a_dst[row] = pd; }
  }

  // C store (fp16): C/D layout col=lane&15, row=(lane>>4)*4+reg
#pragma unroll
  for (int rt = 0; rt < 4; rt++) {
    int rbase = m0 + rt * 16 + q * 4;
#pragma unroll
    for (int ct = 0; ct < 2; ct++) {
      int col = wv * 32 + ct * 16 + l15;
#pragma unroll
      for (int ri = 0; ri < 4; ri++) {
        int row = rbase + ri;
        if (row < N_NODES)
          h1u[(size_t)row * C_HID + col] = f2h(acc[rt][ct][ri]);
      }
    }
  }
}

// ---------------------------------------------------------------------------
// scan: single-block wave-shuffle exclusive scan of (deg+1) -> rowptr.
// ---------------------------------------------------------------------------
__global__ __launch_bounds__(1024) void scan_kernel(const int* __restrict__ deg,
                                                    int* __restrict__ rowptr) {
  __shared__ int wsum[16];
  const int tid = threadIdx.x, lane = tid & 63, wv = tid >> 6;
  int carry = 0;
  for (int base = 0; base < N_NODES; base += 8192) {   // 7 chunks
    int i0 = base + tid * 8;
    int v[8];
    if (i0 + 8 <= N_NODES) {
      int4 va = *(const int4*)(deg + i0);
      int4 vb = *(const int4*)(deg + i0 + 4);
      v[0]=va.x+1; v[1]=va.y+1; v[2]=va.z+1; v[3]=va.w+1;
      v[4]=vb.x+1; v[5]=vb.y+1; v[6]=vb.z+1; v[7]=vb.w+1;
    } else {
#pragma unroll
      for (int i = 0; i < 8; i++) v[i] = (i0 + i < N_NODES) ? deg[i0 + i] + 1 : 0;
    }
    int tsum = 0;
#pragma unroll
    for (int i = 0; i < 8; i++) tsum += v[i];
    int sc = tsum;
#pragma unroll
    for (int off = 1; off < 64; off <<= 1) {
      int t = __shfl_up(sc, off, 64);
      if (lane >= off) sc += t;
    }
    if (lane == 63) wsum[wv] = sc;
    __syncthreads();
    if (wv == 0 && lane < 16) {
      int s = wsum[lane];
#pragma unroll
      for (int off = 1; off < 16; off <<= 1) {
        int t = __shfl_up(s, off, 64);
        if (lane >= off) s += t;
      }
      wsum[lane] = s;
    }
    __syncthreads();
    int ex = carry + (wv ? wsum[wv - 1] : 0) + sc - tsum;
#pragma unroll
    for (int i = 0; i < 8; i++) {
      if (i0 + i < N_NODES) rowptr[i0 + i] = ex;
      ex += v[i];
    }
    carry += wsum[15];
    __syncthreads();
  }
  if (tid == 0) rowptr[N_NODES] = carry;
}

// ---------------------------------------------------------------------------
// bucket: no atomics. Edge e -> slot rowptr[dst]+rank[e]; self-loop n -> slot
// rowptr[n+1]-1. Weight w = exp(leaky(a_src+a_dst)) fused in.
// ---------------------------------------------------------------------------
__global__ void bucket_kernel(const int* __restrict__ ei, const int* __restrict__ rnk,
                              const int* __restrict__ rowptr,
                              const float* __restrict__ a_src, const float* __restrict__ a_dst,
                              int2* __restrict__ esw) {
  int e = blockIdx.x * blockDim.x + threadIdx.x;
  if (e >= E_TOT) return;
  int src, slot;
  if (e < N_EDGES) {
    src = ei[e];
    int dst = ei[N_EDGES + e];
    slot = rowptr[dst] + rnk[e];
    U32H2 c; c.f = __expf(leaky(a_src[src] + a_dst[dst]));
    esw[slot] = make_int2(src, (int)c.u);
  } else {
    int n = e - N_EDGES;
    slot = rowptr[n + 1] - 1;
    U32H2 c; c.f = __expf(leaky(a_src[n] + a_dst[n]));
    esw[slot] = make_int2(n, (int)c.u);
  }
}

// ---------------------------------------------------------------------------
// agg1: wave per node; lane = (q in [0,4), r in [0,16)); lane owns channels
// r*8..r*8+7 (16 B). Inner loop: 16 edges / 4 independent gathers per iter
// (pre-shuffled s,w). W2 rows + bias hoisted to registers once per wave.
// Epilogue: +bias1, ReLU, W2 (128->6), att2 dots -> packed 48-B record
// hs2[n] = {p0..p5, as0..as2, ad0..ad2}.
// ---------------------------------------------------------------------------
__global__ __launch_bounds__(256) void agg1_kernel(const unsigned short* __restrict__ h1u,
    const int2* __restrict__ esw, const int* __restrict__ rowptr,
    const float* __restrict__ bias1, const float* __restrict__ W2,
    const float* __restrict__ as2w, const float* __restrict__ ad2w,
    float* __restrict__ hs2) {
  const int wv = threadIdx.x >> 6, lane = threadIdx.x & 63;
  const int q = lane >> 4, r = lane & 15;
  const int n = blockIdx.x * 4 + wv;               // grid covers N exactly
  const int start = rowptr[n], end = rowptr[n + 1];

  // hoist per-lane constants (channels c = r*8 + j)
  float w2reg[8][6];
#pragma unroll
  for (int j = 0; j < 8; j++) {
    const float* w2r = W2 + (size_t)(r * 8 + j) * 6;
#pragma unroll
    for (int o = 0; o < 6; o++) w2reg[j][o] = w2r[o];
  }
  float4 ba = *(const float4*)(bias1 + r * 8);
  float4 bb = *(const float4*)(bias1 + r * 8 + 4);

  const unsigned short* hbase = h1u + r * 8;

  float acc[8] = {0, 0, 0, 0, 0, 0, 0, 0};
  float wsum = 0.f;
  for (int base = start; base < end; base += 64) {
    int idx = base + lane;
    int sreg = 0; float wreg = 0.f;
    if (idx < end) {
      int2 sv = esw[idx];
      sreg = sv.x;
      U32H2 c; c.u = (unsigned)sv.y;
      wreg = c.f;
    }
    wsum += wreg;
    const int cnt = min(64, end - base);
#pragma unroll
    for (int i = 0; i < 4; i++) {
      if (i * 16 >= cnt) break;                    // wave-uniform guard
      // 16 edges: slots i*16 + 4j + q, j = 0..3  -> 4 independent gathers
      int   s0 = __shfl(sreg, i * 16 + q, 64);
      int   s1 = __shfl(sreg, i * 16 + 4 + q, 64);
      int   s2 = __shfl(sreg, i * 16 + 8 + q, 64);
      int   s3 = __shfl(sreg, i * 16 + 12 + q, 64);
      float w0 = __shfl(wreg, i * 16 + q, 64);
      float w1 = __shfl(wreg, i * 16 + 4 + q, 64);
      float w2 = __shfl(wreg, i * 16 + 8 + q, 64);
      float w3 = __shfl(wreg, i * 16 + 12 + q, 64);
      uint4 g0 = *(const uint4*)(hbase + (size_t)s0 * C_HID);
      uint4 g1 = *(const uint4*)(hbase + (size_t)s1 * C_HID);
      uint4 g2 = *(const uint4*)(hbase + (size_t)s2 * C_HID);
      uint4 g3 = *(const uint4*)(hbase + (size_t)s3 * C_HID);
      U32H2 c0, c1, c2, c3;
#define ACC8(G, W) \
      c0.u = G.x; c1.u = G.y; c2.u = G.z; c3.u = G.w; \
      acc[0] = fmaf(W, (float)c0.h[0], acc[0]); acc[1] = fmaf(W, (float)c0.h[1], acc[1]); \
      acc[2] = fmaf(W, (float)c1.h[0], acc[2]); acc[3] = fmaf(W, (float)c1.h[1], acc[3]); \
      acc[4] = fmaf(W, (float)c2.h[0], acc[4]); acc[5] = fmaf(W, (float)c2.h[1], acc[5]); \
      acc[6] = fmaf(W, (float)c3.h[0], acc[6]); acc[7] = fmaf(W, (float)c3.h[1], acc[7]);
      ACC8(g0, w0) ACC8(g1, w1) ACC8(g2, w2) ACC8(g3, w3)
#undef ACC8
    }
  }

  // fold quarters (q bits): every lane gets full sums for its 8 channels
#pragma unroll
  for (int i = 0; i < 8; i++) {
    acc[i] += __shfl_xor(acc[i], 16, 64);
    acc[i] += __shfl_xor(acc[i], 32, 64);
  }
#pragma unroll
  for (int m = 32; m >= 1; m >>= 1) wsum += __shfl_xor(wsum, m, 64);
  const float inv = 1.f / wsum;                    // > 0 via self-loop

  float u[8] = {fmaxf(acc[0] * inv + ba.x, 0.f), fmaxf(acc[1] * inv + ba.y, 0.f),
                fmaxf(acc[2] * inv + ba.z, 0.f), fmaxf(acc[3] * inv + ba.w, 0.f),
                fmaxf(acc[4] * inv + bb.x, 0.f), fmaxf(acc[5] * inv + bb.y, 0.f),
                fmaxf(acc[6] * inv + bb.z, 0.f), fmaxf(acc[7] * inv + bb.w, 0.f)};
  float p[6] = {0, 0, 0, 0, 0, 0};
#pragma unroll
  for (int j = 0; j < 8; j++)
#pragma unroll
    for (int o = 0; o < 6; o++) p[o] = fmaf(u[j], w2reg[j][o], p[o]);
  // fold over r (lane bits 0..3)
#pragma unroll
  for (int o = 0; o < 6; o++) {
    p[o] += __shfl_xor(p[o], 1, 64);
    p[o] += __shfl_xor(p[o], 2, 64);
    p[o] += __shfl_xor(p[o], 4, 64);
    p[o] += __shfl_xor(p[o], 8, 64);
  }

  if (lane == 0) {
    float as0 = p[0] * as2w[0] + p[1] * as2w[1];
    float as1 = p[2] * as2w[2] + p[3] * as2w[3];
    float as2_ = p[4] * as2w[4] + p[5] * as2w[5];
    float ad0 = p[0] * ad2w[0] + p[1] * ad2w[1];
    float ad1 = p[2] * ad2w[2] + p[3] * ad2w[3];
    float ad2_ = p[4] * ad2w[4] + p[5] * ad2w[5];
    float* dst = hs2 + (size_t)n * 12;
    *(float4*)(dst)     = make_float4(p[0], p[1], p[2], p[3]);
    *(float4*)(dst + 4) = make_float4(p[4], p[5], as0, as1);
    *(float4*)(dst + 8) = make_float4(as2_, ad0, ad1, ad2_);
  }
}

// ---------------------------------------------------------------------------
// agg2: 16 lanes per node (4 nodes/wave); per edge ONE 48-B packed record
// {p0..p5, as0..as2} (3 loads, 1-2 lines). out = mean over heads + bias2.
// ---------------------------------------------------------------------------
__global__ __launch_bounds__(256) void agg2_kernel(const float* __restrict__ hs2,
    const int* __restrict__ rowptr, const int2* __restrict__ esw,
    const float* __restrict__ bias2, float* __restrict__ out) {
  const int wv = threadIdx.x >> 6, lane = threadIdx.x & 63;
  const int q = lane >> 4, r = lane & 15;
  const int n = blockIdx.x * 16 + wv * 4 + q;
  if (n >= N_NODES) return;
  const int start = rowptr[n], end = rowptr[n + 1];
  float4 own = *(const float4*)(hs2 + (size_t)n * 12 + 8);   // {as2, ad0, ad1, ad2}
  const float ad0 = own.y, ad1 = own.z, ad2 = own.w;

  float d0 = 0.f, d1 = 0.f, d2 = 0.f;
  float a0 = 0.f, a1 = 0.f, a2 = 0.f, a3 = 0.f, a4 = 0.f, a5 = 0.f;
  for (int j = start + r; j < end; j += 16) {
    int s = esw[j].x;
    const float* rec = hs2 + (size_t)s * 12;
    float4 A = *(const float4*)(rec);          // p0..p3
    float4 B = *(const float4*)(rec + 4);      // p4, p5, as0, as1
    float  C = rec[8];                         // as2
    float e0 = __expf(leaky(B.z + ad0));
    float e1 = __expf(leaky(B.w + ad1));
    float e2 = __expf(leaky(C + ad2));
    d0 += e0; d1 += e1; d2 += e2;
    a0 += e0 * A.x; a1 += e0 * A.y;
    a2 += e1 * A.z; a3 += e1 * A.w;
    a4 += e2 * B.x; a5 += e2 * B.y;
  }
#pragma unroll
  for (int m = 8; m >= 1; m >>= 1) {
    d0 += __shfl_xor(d0, m, 64); d1 += __shfl_xor(d1, m, 64); d2 += __shfl_xor(d2, m, 64);
    a0 += __shfl_xor(a0, m, 64); a1 += __shfl_xor(a1, m, 64); a2 += __shfl_xor(a2, m, 64);
    a3 += __shfl_xor(a3, m, 64); a4 += __shfl_xor(a4, m, 64); a5 += __shfl_xor(a5, m, 64);
  }
  if (r == 0) {
    float o0 = (a0 / d0 + a2 / d1 + a4 / d2) * (1.f / 3.f) + bias2[0];
    float o1 = (a1 / d0 + a3 / d1 + a5 / d2) * (1.f / 3.f) + bias2[1];
    *(float2*)(out + (size_t)n * 2) = make_float2(o0, o1);
  }
}

// ---------------------------------------------------------------------------
extern "C" void kernel_launch(void* const* d_in, const int* in_sizes, int n_in,
                              void* d_out, int out_size, void* d_ws, size_t ws_size,
                              hipStream_t stream) {
  const float* x        = (const float*)d_in[0];
  const int*   ei       = (const int*)d_in[1];
  const float* W1       = (const float*)d_in[2];
  const float* att_src1 = (const float*)d_in[3];
  const float* att_dst1 = (const float*)d_in[4];
  const float* bias1    = (const float*)d_in[5];
  const float* W2       = (const float*)d_in[6];
  const float* att_src2 = (const float*)d_in[7];
  const float* att_dst2 = (const float*)d_in[8];
  const float* bias2    = (const float*)d_in[9];
  float* out = (float*)d_out;

  char* w = (char*)d_ws;
  auto alloc = [&](size_t bytes) {
    char* p = w;
    w += (bytes + 255) & ~(size_t)255;
    return p;
  };
  unsigned short* h1u    = (unsigned short*)alloc((size_t)N_NODES * C_HID * 2);  // 12.8 MB
  unsigned short* Wswz   = (unsigned short*)alloc((size_t)C_IN * C_HID * 2 * 2); // 256 KB
  float*          v1s    = (float*)alloc((size_t)C_IN * 4);
  float*          v1d    = (float*)alloc((size_t)C_IN * 4);
  float*          a_src1 = (float*)alloc((size_t)N_NODES * 4);
  float*          a_dst1 = (float*)alloc((size_t)N_NODES * 4);
  int*            deg    = (int*)alloc((size_t)N_NODES * 4);
  int*            rowptr = (int*)alloc((size_t)(N_NODES + 4) * 4);
  int*            rnk    = (int*)alloc((size_t)N_EDGES * 4);                     // 3.2 MB
  int2*           esw    = (int2*)alloc((size_t)E_TOT * 8);                      // 6.8 MB
  float*          hs2    = (float*)alloc((size_t)N_NODES * 12 * 4);              // 2.4 MB

  (void)hipMemsetAsync(deg, 0, (size_t)N_NODES * 4, stream);

  setup_kernel<<<160 + (N_EDGES + 255) / 256, 256, 0, stream>>>(
      W1, att_src1, att_dst1, ei, Wswz, v1s, v1d, deg, rnk);
  scan_kernel<<<1, 1024, 0, stream>>>(deg, rowptr);
  lin1_kernel<<<(N_NODES + 63) / 64, 256, 0, stream>>>(x, Wswz, v1s, v1d,
                                                       h1u, a_src1, a_dst1);
  bucket_kernel<<<(E_TOT + 255) / 256, 256, 0, stream>>>(ei, rnk, rowptr,
                                                         a_src1, a_dst1, esw);
  agg1_kernel<<<N_NODES / 4, 256, 0, stream>>>(h1u, esw, rowptr, bias1, W2,
                                               att_src2, att_dst2, hs2);
  agg2_kernel<<<(N_NODES + 15) / 16, 256, 0, stream>>>(hs2, rowptr, esw, bias2, out);
}